// Round 19
// baseline (438.156 us; speedup 1.0000x reference)
//
#include <hip/hip_runtime.h>
#include <math.h>

#define D    6
#define S    128
#define H    128
#define WIN  16
#define BB   8
#define TT   513
#define NW   32
#define OUTD 10

// ---- device-global scratch ----
__device__ float g_lvl1[BB * NW * D];
__device__ float g_area[BB * NW * D * D];
__device__ float g_h0[BB * S];
__device__ float g_hist[BB * (NW + 1) * S];
__device__ float4 g_W2p[3 * 16 * 512];   // packed W2: [ptr][quad i][tid]

__device__ __forceinline__ float sp(float x) {
    return (x > 20.f) ? x : log1pf(expf(x));
}
__device__ __forceinline__ float sigm(float x) {
    return 1.f / (1.f + expf(-x));
}
__device__ __forceinline__ float dot4(float4 a, float4 b, float acc) {
    return fmaf(a.x, b.x, fmaf(a.y, b.y, fmaf(a.z, b.z, fmaf(a.w, b.w, acc))));
}

// ---- LDS layout (float offsets) ----
#define O_W0   0        // [128 r][128 k] fp32 row-major
#define O_W1   16384
#define O_V    32768    // [768]
#define O_T1   33536    // [6][128] T1; later bterm
#define O_T2   34304    // [6][128] T2
#define O_H    35072    // [128] h (single buffer)
#define O_U1   35200
#define O_SG1  35328
#define O_U2   35456
#define O_SG2  35584
#define O_B0   35712
#define O_B1   35840
#define O_B2   35968    // [768]
#define O_SIG  36736    // [2][44]
#define SMTOT  36824    // 147,296 B

// ---- K0: pack W2 into per-thread coalesced streaming order ----
__global__ __launch_bounds__(512) void k_pack(const float* __restrict__ Wv2) {
    const float4* W24 = (const float4*)Wv2;          // [768][32]
    int e = blockIdx.x * 512 + threadIdx.x;
    if (e < 3 * 16 * 512) {
        int ptr = e >> 13;
        int rem = e & 8191;
        int i   = rem >> 9;
        int tid = rem & 511;
        int r0 = tid >> 1, kh = tid & 1;
        int row = r0 + ptr * 256;
        g_W2p[e] = W24[row * 32 + kh * 16 + i];
    }
}

// ---- K2: windowed log-signature + init MLP ----
__global__ __launch_bounds__(256) void k_sig(
        const float* __restrict__ x,
        const float* __restrict__ Wi0, const float* __restrict__ bi0,
        const float* __restrict__ Wi1, const float* __restrict__ bi1,
        const float* __restrict__ Wi2, const float* __restrict__ bi2) {
    const int b = blockIdx.x;
    const int tid = threadIdx.x;
    __shared__ float dxs[NW][WIN][D];
    __shared__ float cums[NW][WIN][D];
    __shared__ float ua[H], ub[H];

    const float* xb = x + (size_t)b * TT * D;

    if (tid < NW * D) {
        int w = tid / D, i = tid % D;
        float run = 0.f;
        float prev = xb[(w * WIN) * D + i];
        for (int k = 0; k < WIN; ++k) {
            float cur = xb[(w * WIN + k + 1) * D + i];
            float d = cur - prev; prev = cur;
            dxs[w][k][i] = d;
            cums[w][k][i] = run;
            run += d;
        }
        g_lvl1[(b * NW + w) * D + i] = run;
    }
    __syncthreads();
    for (int e = tid; e < NW * D * D; e += blockDim.x) {
        int w = e / (D * D); int rem = e % (D * D);
        int i = rem / D, j = rem % D;
        float s = 0.f;
        for (int k = 0; k < WIN; ++k)
            s += cums[w][k][i] * dxs[w][k][j] - cums[w][k][j] * dxs[w][k][i];
        g_area[(b * NW + w) * (D * D) + rem] = 0.5f * s;
    }
    if (tid < H) {
        float z = bi0[tid];
        for (int k = 0; k < D; ++k) z += Wi0[tid * D + k] * xb[k];
        ua[tid] = sp(z);
    }
    __syncthreads();
    if (tid < H) {
        float z = bi1[tid];
        for (int k = 0; k < H; ++k) z += Wi1[tid * H + k] * ua[k];
        ub[tid] = sp(z);
    }
    __syncthreads();
    if (tid < H) {
        float z = bi2[tid];
        for (int k = 0; k < H; ++k) z += Wi2[tid * H + k] * ub[k];
        g_h0[b * S + tid] = z;
    }
}

// ---- K3: 8 blocks x 512 threads; 7 barrier-phases/step ----
__global__ __launch_bounds__(512, 2) void k_scan(
        const float* __restrict__ bv0, const float* __restrict__ bv1,
        const float* __restrict__ bv2,
        const float* __restrict__ Wv0, const float* __restrict__ Wv1) {
    __shared__ float sm[SMTOT];
    const int tid = threadIdx.x;
    const int b = blockIdx.x;
    // A-stage mapping: row r, k-quarter sub (lane-adjacent -> shfl-reducible)
    const int r = tid >> 2, sub = tid & 3, key = r & 7;
    // W2-stage mapping: k-half kh (lane-adjacent), row triple r0
    const int kh = tid & 1, r0 = tid >> 1;
    const int jA = r0 >> 7;

    // stage W0, W1, biases
    {
        float4* d = (float4*)(sm + O_W0);
        const float4* s0 = (const float4*)Wv0;
        const float4* s1 = (const float4*)Wv1;
        #pragma unroll
        for (int i = 0; i < 8; ++i) d[tid + i * 512] = s0[tid + i * 512];
        #pragma unroll
        for (int i = 0; i < 8; ++i) d[4096 + tid + i * 512] = s1[tid + i * 512];
        sm[O_B2 + tid] = bv2[tid];
        if (tid < 256) sm[O_B2 + 512 + tid] = bv2[512 + tid];
        if (tid < 128) { sm[O_B0 + tid] = bv0[tid]; sm[O_B1 + tid] = bv1[tid]; }
    }
    const float4* WAp = g_W2p + tid;
    const float4* WBp = g_W2p + 8192 + tid;
    const float4* WCp = g_W2p + 16384 + tid;
    if (tid < 128) {
        float h0v = g_h0[b * 128 + tid];
        sm[O_H + tid] = h0v;
        g_hist[(b * (NW + 1)) * 128 + tid] = h0v;
    }
    if (tid >= 448) {
        int q = tid - 448;
        if (q < 42)
            sm[O_SIG + q] = (q < 6) ? g_lvl1[(b * NW) * 6 + q]
                                    : g_area[(b * NW) * 36 + q - 6];
    }
    __syncthreads();

    const float4* W04 = (const float4*)(sm + O_W0);
    const float4* W14 = (const float4*)(sm + O_W1);

    for (int t = 0; t < NW; ++t) {
        // prefetch sig for t+1 (stored at H)
        float rsig = 0.f;
        if (tid >= 448) {
            int q = tid - 448;
            if (q < 42 && t + 1 < NW)
                rsig = (q < 6) ? g_lvl1[(b * NW + t + 1) * 6 + q]
                               : g_area[(b * NW + t + 1) * 36 + q - 6];
        }
        const int sb = O_SIG + (t & 1) * 44;

        // ---- P1: z1 = W0.h -> u1, sg1 (shfl-merged) ----
        {
            float a = 0.f;
            const float4* H4 = (const float4*)(sm + O_H);
            #pragma unroll
            for (int q = 0; q < 8; ++q) {
                int qq = sub * 8 + (q ^ key);
                a = dot4(W04[r * 32 + qq], H4[qq], a);
            }
            a += __shfl_xor(a, 1); a += __shfl_xor(a, 2);
            if (sub == 0)      sm[O_U1 + r]  = sp(sm[O_B0 + r] + a);
            else if (sub == 1) sm[O_SG1 + r] = sigm(sm[O_B0 + r] + a);
        }
        __syncthreads();
        // ---- P2: z2 = W1.u1 -> u2, sg2 ----
        {
            float a = 0.f;
            const float4* U14 = (const float4*)(sm + O_U1);
            #pragma unroll
            for (int q = 0; q < 8; ++q) {
                int qq = sub * 8 + (q ^ key);
                a = dot4(W14[r * 32 + qq], U14[qq], a);
            }
            a += __shfl_xor(a, 1); a += __shfl_xor(a, 2);
            if (sub == 0)      sm[O_U2 + r]  = sp(sm[O_B1 + r] + a);
            else if (sub == 1) sm[O_SG2 + r] = sigm(sm[O_B1 + r] + a);
        }
        __syncthreads();
        // ---- P3: V = tanh(W2.u2 + b2) (packed stream + shfl) ----
        {
            float acc0 = 0.f, acc1 = 0.f, acc2 = 0.f;
            const float4* U24 = (const float4*)(sm + O_U2) + kh * 16;
            #pragma unroll 4
            for (int i = 0; i < 16; ++i) {
                float4 u = U24[i];
                acc0 = dot4(WAp[i * 512], u, acc0);
                acc1 = dot4(WBp[i * 512], u, acc1);
                acc2 = dot4(WCp[i * 512], u, acc2);
            }
            acc0 += __shfl_xor(acc0, 1);
            acc1 += __shfl_xor(acc1, 1);
            acc2 += __shfl_xor(acc2, 1);
            if (kh == 0) {
                sm[O_V + r0]       = tanhf(sm[O_B2 + r0] + acc0);
                sm[O_V + r0 + 256] = tanhf(sm[O_B2 + r0 + 256] + acc1);
            } else {
                sm[O_V + r0 + 512] = tanhf(sm[O_B2 + r0 + 512] + acc2);
            }
        }
        __syncthreads();
        // ---- P4: Y_i = W0.V_i ; T1_j = sg1 .* sum_i a[i][j] Y_i (area folded late) ----
        {
            float y0 = 0, y1 = 0, y2 = 0, y3 = 0, y4 = 0, y5 = 0;
            const float4* V4 = (const float4*)(sm + O_V);
            #pragma unroll
            for (int q = 0; q < 8; ++q) {
                int qq = sub * 8 + (q ^ key);
                float4 w = W04[r * 32 + qq];
                y0 = dot4(w, V4[qq], y0);
                y1 = dot4(w, V4[32 + qq], y1);
                y2 = dot4(w, V4[64 + qq], y2);
                y3 = dot4(w, V4[96 + qq], y3);
                y4 = dot4(w, V4[128 + qq], y4);
                y5 = dot4(w, V4[160 + qq], y5);
            }
            y0 += __shfl_xor(y0, 1); y0 += __shfl_xor(y0, 2);
            y1 += __shfl_xor(y1, 1); y1 += __shfl_xor(y1, 2);
            y2 += __shfl_xor(y2, 1); y2 += __shfl_xor(y2, 2);
            y3 += __shfl_xor(y3, 1); y3 += __shfl_xor(y3, 2);
            y4 += __shfl_xor(y4, 1); y4 += __shfl_xor(y4, 2);
            y5 += __shfl_xor(y5, 1); y5 += __shfl_xor(y5, 2);
            if (sub < 3) {
                const int j0 = 2 * sub, j1 = j0 + 1;
                const float* A0 = sm + sb + 6;
                float sg = sm[O_SG1 + r];
                float t0 = fmaf(A0[j0], y0, 0.f);
                t0 = fmaf(A0[6 + j0], y1, t0);
                t0 = fmaf(A0[12 + j0], y2, t0);
                t0 = fmaf(A0[18 + j0], y3, t0);
                t0 = fmaf(A0[24 + j0], y4, t0);
                t0 = fmaf(A0[30 + j0], y5, t0);
                float t1 = fmaf(A0[j1], y0, 0.f);
                t1 = fmaf(A0[6 + j1], y1, t1);
                t1 = fmaf(A0[12 + j1], y2, t1);
                t1 = fmaf(A0[18 + j1], y3, t1);
                t1 = fmaf(A0[24 + j1], y4, t1);
                t1 = fmaf(A0[30 + j1], y5, t1);
                sm[O_T1 + j0 * 128 + r] = sg * t0;
                sm[O_T1 + j1 * 128 + r] = sg * t1;
            }
        }
        __syncthreads();
        // ---- P5: T2_j = sg2 .* (W1.T1_j) ----
        {
            float z0 = 0, z1 = 0, z2 = 0, z3 = 0, z4 = 0, z5 = 0;
            const float4* T4 = (const float4*)(sm + O_T1);
            #pragma unroll
            for (int q = 0; q < 8; ++q) {
                int qq = sub * 8 + (q ^ key);
                float4 w = W14[r * 32 + qq];
                z0 = dot4(w, T4[qq], z0);
                z1 = dot4(w, T4[32 + qq], z1);
                z2 = dot4(w, T4[64 + qq], z2);
                z3 = dot4(w, T4[96 + qq], z3);
                z4 = dot4(w, T4[128 + qq], z4);
                z5 = dot4(w, T4[160 + qq], z5);
            }
            z0 += __shfl_xor(z0, 1); z0 += __shfl_xor(z0, 2);
            z1 += __shfl_xor(z1, 1); z1 += __shfl_xor(z1, 2);
            z2 += __shfl_xor(z2, 1); z2 += __shfl_xor(z2, 2);
            z3 += __shfl_xor(z3, 1); z3 += __shfl_xor(z3, 2);
            z4 += __shfl_xor(z4, 1); z4 += __shfl_xor(z4, 2);
            z5 += __shfl_xor(z5, 1); z5 += __shfl_xor(z5, 2);
            float sg = sm[O_SG2 + r];
            if (sub == 0) {
                sm[O_T2 + 0 * 128 + r] = sg * z0;
                sm[O_T2 + 1 * 128 + r] = sg * z1;
            } else if (sub == 1) {
                sm[O_T2 + 2 * 128 + r] = sg * z2;
                sm[O_T2 + 3 * 128 + r] = sg * z3;
            } else if (sub == 2) {
                sm[O_T2 + 4 * 128 + r] = sg * z4;
                sm[O_T2 + 5 * 128 + r] = sg * z5;
            }
        }
        __syncthreads();
        // ---- P6: bterm = (1-V^2).*(W2.T2_j(row)) (packed stream + shfl, into O_T1) ----
        {
            float acc0 = 0.f, acc1 = 0.f, acc2 = 0.f;
            const float4* TA = (const float4*)(sm + O_T2) + jA * 32 + kh * 16;
            const float4* TB = (const float4*)(sm + O_T2) + (2 + jA) * 32 + kh * 16;
            const float4* TC = (const float4*)(sm + O_T2) + (4 + jA) * 32 + kh * 16;
            #pragma unroll 4
            for (int i = 0; i < 16; ++i) {
                acc0 = dot4(WAp[i * 512], TA[i], acc0);
                acc1 = dot4(WBp[i * 512], TB[i], acc1);
                acc2 = dot4(WCp[i * 512], TC[i], acc2);
            }
            acc0 += __shfl_xor(acc0, 1);
            acc1 += __shfl_xor(acc1, 1);
            acc2 += __shfl_xor(acc2, 1);
            if (kh == 0) {
                float v0 = sm[O_V + r0];
                float v1 = sm[O_V + r0 + 256];
                sm[O_T1 + r0]       = (1.f - v0 * v0) * acc0;
                sm[O_T1 + r0 + 256] = (1.f - v1 * v1) * acc1;
            } else {
                float v2 = sm[O_V + r0 + 512];
                sm[O_T1 + r0 + 512] = (1.f - v2 * v2) * acc2;
            }
        }
        __syncthreads();
        // ---- P7: h += l1.V + sum_j bterm_j ; hist; store prefetched sig ----
        if (tid < 128) {
            float xh = sm[O_H + tid];
            #pragma unroll
            for (int i = 0; i < 6; ++i)
                xh = fmaf(sm[sb + i], sm[O_V + i * 128 + tid], xh);
            #pragma unroll
            for (int j = 0; j < 6; ++j) xh += sm[O_T1 + j * 128 + tid];
            sm[O_H + tid] = xh;
            g_hist[(b * (NW + 1) + t + 1) * 128 + tid] = xh;
        }
        if (tid >= 448) {
            int q = tid - 448;
            if (q < 42 && t + 1 < NW)
                sm[O_SIG + ((t + 1) & 1) * 44 + q] = rsig;
        }
        __syncthreads();
    }
}

// ---- K4: readout ----
__global__ __launch_bounds__(384) void k_read(const float* __restrict__ Wr,
                                              const float* __restrict__ br,
                                              float* __restrict__ out) {
    const int b = blockIdx.x, e = threadIdx.x;
    if (e < (NW + 1) * OUTD) {
        int t = e / OUTD, o = e % OUTD;
        float z = br[o];
        const float4* hrow = (const float4*)&g_hist[(b * (NW + 1) + t) * 128];
        const float4* wrow = (const float4*)&Wr[o * 128];
        float z0 = 0, z1 = 0, z2 = 0, z3 = 0;
        #pragma unroll 8
        for (int s4 = 0; s4 < 32; ++s4) {
            float4 hv = hrow[s4]; float4 wv = wrow[s4];
            z0 = fmaf(hv.x, wv.x, z0); z1 = fmaf(hv.y, wv.y, z1);
            z2 = fmaf(hv.z, wv.z, z2); z3 = fmaf(hv.w, wv.w, z3);
        }
        out[(b * (NW + 1) + t) * OUTD + o] = z + ((z0 + z1) + (z2 + z3));
    }
}

extern "C" void kernel_launch(void* const* d_in, const int* in_sizes, int n_in,
                              void* d_out, int out_size, void* d_ws, size_t ws_size,
                              hipStream_t stream) {
    const float* x   = (const float*)d_in[0];
    const float* Wi0 = (const float*)d_in[1];
    const float* bi0 = (const float*)d_in[2];
    const float* Wi1 = (const float*)d_in[3];
    const float* bi1 = (const float*)d_in[4];
    const float* Wi2 = (const float*)d_in[5];
    const float* bi2 = (const float*)d_in[6];
    const float* Wv0 = (const float*)d_in[7];
    const float* bv0 = (const float*)d_in[8];
    const float* Wv1 = (const float*)d_in[9];
    const float* bv1 = (const float*)d_in[10];
    const float* Wv2 = (const float*)d_in[11];
    const float* bv2 = (const float*)d_in[12];
    const float* Wr  = (const float*)d_in[13];
    const float* br  = (const float*)d_in[14];
    float* out = (float*)d_out;

    hipLaunchKernelGGL(k_pack, dim3(48), dim3(512), 0, stream, Wv2);
    hipLaunchKernelGGL(k_sig,  dim3(BB), dim3(256), 0, stream,
                       x, Wi0, bi0, Wi1, bi1, Wi2, bi2);
    hipLaunchKernelGGL(k_scan, dim3(BB), dim3(512), 0, stream,
                       bv0, bv1, bv2, Wv0, Wv1);
    hipLaunchKernelGGL(k_read, dim3(BB), dim3(384), 0, stream, Wr, br, out);
}

// Round 20
// 387.231 us; speedup vs baseline: 1.1315x; 1.1315x over previous
//
#include <hip/hip_runtime.h>
#include <math.h>

#define D    6
#define S    128
#define H    128
#define WIN  16
#define BB   8
#define TT   513
#define NW   32
#define OUTD 10

// ---- device-global scratch ----
__device__ float g_lvl1[BB * NW * D];
__device__ float g_area[BB * NW * D * D];
__device__ float g_h0[BB * S];
__device__ float g_hist[BB * (NW + 1) * S];
__device__ float4 g_W2p[3 * 16 * 512];   // packed W2: [ptr][quad i][tid]

__device__ __forceinline__ float sp(float x) {
    return (x > 20.f) ? x : log1pf(expf(x));
}
__device__ __forceinline__ float sigm(float x) {
    return 1.f / (1.f + expf(-x));
}
__device__ __forceinline__ float dot4(float4 a, float4 b, float acc) {
    return fmaf(a.x, b.x, fmaf(a.y, b.y, fmaf(a.z, b.z, fmaf(a.w, b.w, acc))));
}

// ---- LDS layout (float offsets) ----
#define O_W0   0        // [128 r][128 k] fp32 row-major
#define O_W1   16384
#define O_PS   32768    // psum [4 c][6 i][128 r] (3072); aliased psumV [2][768]
#define O_U    35840    // [6][128] T2
#define O_T    36608    // [6][128] T1
#define O_V    37376    // [768]
#define O_H    38144    // [128] h single buffer
#define O_U1   38400
#define O_U2   38528
#define O_SG1  38656
#define O_SG2  38784
#define O_B0   38912
#define O_B1   39040
#define O_SIG  39168    // [2][44]
#define O_B2   39256    // [768] bv2 staged
#define SMTOT  40024    // 160,096 B

// ---- K0: pack W2 into per-thread coalesced streaming order ----
__global__ __launch_bounds__(512) void k_pack(const float* __restrict__ Wv2) {
    const float4* W24 = (const float4*)Wv2;          // [768][32]
    int e = blockIdx.x * 512 + threadIdx.x;
    if (e < 3 * 16 * 512) {
        int ptr = e >> 13;
        int rem = e & 8191;
        int i   = rem >> 9;
        int tid = rem & 511;
        int r0 = tid >> 1, kh = tid & 1;
        int row = r0 + ptr * 256;
        g_W2p[e] = W24[row * 32 + kh * 16 + i];
    }
}

// ---- K2: windowed log-signature + init MLP ----
__global__ __launch_bounds__(256) void k_sig(
        const float* __restrict__ x,
        const float* __restrict__ Wi0, const float* __restrict__ bi0,
        const float* __restrict__ Wi1, const float* __restrict__ bi1,
        const float* __restrict__ Wi2, const float* __restrict__ bi2) {
    const int b = blockIdx.x;
    const int tid = threadIdx.x;
    __shared__ float dxs[NW][WIN][D];
    __shared__ float cums[NW][WIN][D];
    __shared__ float ua[H], ub[H];

    const float* xb = x + (size_t)b * TT * D;

    if (tid < NW * D) {
        int w = tid / D, i = tid % D;
        float run = 0.f;
        float prev = xb[(w * WIN) * D + i];
        for (int k = 0; k < WIN; ++k) {
            float cur = xb[(w * WIN + k + 1) * D + i];
            float d = cur - prev; prev = cur;
            dxs[w][k][i] = d;
            cums[w][k][i] = run;
            run += d;
        }
        g_lvl1[(b * NW + w) * D + i] = run;
    }
    __syncthreads();
    for (int e = tid; e < NW * D * D; e += blockDim.x) {
        int w = e / (D * D); int rem = e % (D * D);
        int i = rem / D, j = rem % D;
        float s = 0.f;
        for (int k = 0; k < WIN; ++k)
            s += cums[w][k][i] * dxs[w][k][j] - cums[w][k][j] * dxs[w][k][i];
        g_area[(b * NW + w) * (D * D) + rem] = 0.5f * s;
    }
    if (tid < H) {
        float z = bi0[tid];
        for (int k = 0; k < D; ++k) z += Wi0[tid * D + k] * xb[k];
        ua[tid] = sp(z);
    }
    __syncthreads();
    if (tid < H) {
        float z = bi1[tid];
        for (int k = 0; k < H; ++k) z += Wi1[tid * H + k] * ua[k];
        ub[tid] = sp(z);
    }
    __syncthreads();
    if (tid < H) {
        float z = bi2[tid];
        for (int k = 0; k < H; ++k) z += Wi2[tid * H + k] * ub[k];
        g_h0[b * S + tid] = z;
    }
}

// ---- K3: 8 blocks x 512 threads; 12 barrier-phases/step; r18 lane mappings ----
__global__ __launch_bounds__(512, 2) void k_scan(
        const float* __restrict__ bv0, const float* __restrict__ bv1,
        const float* __restrict__ bv2,
        const float* __restrict__ Wv0, const float* __restrict__ Wv1) {
    __shared__ float sm[SMTOT];
    const int tid = threadIdx.x;
    const int b = blockIdx.x;
    const int r   = tid & 127;       // row for W0/W1 psum stages (wave-uniform chunk)
    const int c4  = tid >> 7;        // k-chunk 0..3 (uniform per wave)
    const int key = r & 7;
    const int kh = tid & 1;
    const int r0 = tid >> 1, r1 = r0 + 256, r2 = r0 + 512;
    const int jA = tid >> 8, jB = 2 + jA, jC = 4 + jA;

    // stage W0, W1, biases
    {
        float4* d = (float4*)(sm + O_W0);
        const float4* s0 = (const float4*)Wv0;
        const float4* s1 = (const float4*)Wv1;
        for (int i = tid; i < 4096; i += 512) { d[i] = s0[i]; d[4096 + i] = s1[i]; }
        sm[O_B2 + tid] = bv2[tid];
        if (tid < 256) sm[O_B2 + 512 + tid] = bv2[512 + tid];
        if (tid < 128) { sm[O_B0 + tid] = bv0[tid]; sm[O_B1 + tid] = bv1[tid]; }
    }
    const float4* WAp = g_W2p + tid;
    const float4* WBp = g_W2p + 8192 + tid;
    const float4* WCp = g_W2p + 16384 + tid;
    if (tid < 128) {
        float h0v = g_h0[b * 128 + tid];
        sm[O_H + tid] = h0v;
        g_hist[(b * (NW + 1)) * 128 + tid] = h0v;
    }
    if (tid >= 448) {
        int q = tid - 448;
        if (q < 42)
            sm[O_SIG + q] = (q < 6) ? g_lvl1[(b * NW) * 6 + q]
                                    : g_area[(b * NW) * 36 + q - 6];
    }
    __syncthreads();

    const float4* W04 = (const float4*)(sm + O_W0);
    const float4* W14 = (const float4*)(sm + O_W1);

    for (int t = 0; t < NW; ++t) {
        float rsig = 0.f;
        if (tid >= 448) {
            int q = tid - 448;
            if (q < 42 && t + 1 < NW)
                rsig = (q < 6) ? g_lvl1[(b * NW + t + 1) * 6 + q]
                               : g_area[(b * NW + t + 1) * 36 + q - 6];
        }
        const int sb = O_SIG + (t & 1) * 44;

        // ---- S1: psum = W0 . h ----
        {
            float a = 0.f;
            const float4* H4 = (const float4*)(sm + O_H);
            #pragma unroll
            for (int q = 0; q < 8; ++q) {
                int qq = c4 * 8 + (q ^ key);
                a = dot4(W04[r * 32 + qq], H4[qq], a);
            }
            sm[O_PS + (c4 * 6) * 128 + r] = a;
        }
        __syncthreads();
        // ---- R1 ----
        if (tid < 128) {
            float z = sm[O_B0 + tid];
            #pragma unroll
            for (int c = 0; c < 4; ++c) z += sm[O_PS + (c * 6) * 128 + tid];
            sm[O_U1 + tid] = sp(z); sm[O_SG1 + tid] = sigm(z);
        }
        __syncthreads();
        // ---- S2: psum = W1 . u1 ----
        {
            float a = 0.f;
            const float4* U14 = (const float4*)(sm + O_U1);
            #pragma unroll
            for (int q = 0; q < 8; ++q) {
                int qq = c4 * 8 + (q ^ key);
                a = dot4(W14[r * 32 + qq], U14[qq], a);
            }
            sm[O_PS + (c4 * 6) * 128 + r] = a;
        }
        __syncthreads();
        // ---- R2 ----
        if (tid < 128) {
            float z = sm[O_B1 + tid];
            #pragma unroll
            for (int c = 0; c < 4; ++c) z += sm[O_PS + (c * 6) * 128 + tid];
            sm[O_U2 + tid] = sp(z); sm[O_SG2 + tid] = sigm(z);
        }
        __syncthreads();
        // ---- S3: psumV = W2 . u2 (packed coalesced stream) ----
        {
            float acc0 = 0.f, acc1 = 0.f, acc2 = 0.f;
            const float4* U24 = (const float4*)(sm + O_U2) + kh * 16;
            #pragma unroll 4
            for (int i = 0; i < 16; ++i) {
                float4 u = U24[i];
                acc0 = dot4(WAp[i * 512], u, acc0);
                acc1 = dot4(WBp[i * 512], u, acc1);
                acc2 = dot4(WCp[i * 512], u, acc2);
            }
            sm[O_PS + kh * 768 + r0] = acc0;
            sm[O_PS + kh * 768 + r1] = acc1;
            sm[O_PS + kh * 768 + r2] = acc2;
        }
        __syncthreads();
        // ---- R3: V = tanh(b2 + psV0 + psV1) ----
        {
            sm[O_V + tid] = tanhf(sm[O_B2 + tid] + sm[O_PS + tid] + sm[O_PS + 768 + tid]);
            if (tid < 256) {
                int e = tid + 512;
                sm[O_V + e] = tanhf(sm[O_B2 + e] + sm[O_PS + e] + sm[O_PS + 768 + e]);
            }
        }
        __syncthreads();
        // ---- S4: psum[c][i][r] = W0[r,chunk] . V_i  (V read directly; UF eliminated) ----
        {
            float a0 = 0.f, a1 = 0.f, a2 = 0.f, a3 = 0.f, a4 = 0.f, a5 = 0.f;
            const float4* V4 = (const float4*)(sm + O_V);
            #pragma unroll
            for (int q = 0; q < 8; ++q) {
                int qq = c4 * 8 + (q ^ key);
                float4 w = W04[r * 32 + qq];
                a0 = dot4(w, V4[qq], a0);
                a1 = dot4(w, V4[32 + qq], a1);
                a2 = dot4(w, V4[64 + qq], a2);
                a3 = dot4(w, V4[96 + qq], a3);
                a4 = dot4(w, V4[128 + qq], a4);
                a5 = dot4(w, V4[160 + qq], a5);
            }
            sm[O_PS + (c4 * 6 + 0) * 128 + r] = a0;
            sm[O_PS + (c4 * 6 + 1) * 128 + r] = a1;
            sm[O_PS + (c4 * 6 + 2) * 128 + r] = a2;
            sm[O_PS + (c4 * 6 + 3) * 128 + r] = a3;
            sm[O_PS + (c4 * 6 + 4) * 128 + r] = a4;
            sm[O_PS + (c4 * 6 + 5) * 128 + r] = a5;
        }
        __syncthreads();
        // ---- R4': T1_j = sg1 .* sum_i area[i][j] * Y_i  (area folded on reduced scalars) ----
        {
            #pragma unroll
            for (int s = 0; s < 2; ++s) {
                int e = tid + s * 512;
                if (s == 0 || tid < 256) {
                    int jj = e >> 7, rr = e & 127;
                    float y0 = sm[O_PS + 0 * 128 + rr] + sm[O_PS + (6 + 0) * 128 + rr]
                             + sm[O_PS + (12 + 0) * 128 + rr] + sm[O_PS + (18 + 0) * 128 + rr];
                    float y1 = sm[O_PS + 1 * 128 + rr] + sm[O_PS + (6 + 1) * 128 + rr]
                             + sm[O_PS + (12 + 1) * 128 + rr] + sm[O_PS + (18 + 1) * 128 + rr];
                    float y2 = sm[O_PS + 2 * 128 + rr] + sm[O_PS + (6 + 2) * 128 + rr]
                             + sm[O_PS + (12 + 2) * 128 + rr] + sm[O_PS + (18 + 2) * 128 + rr];
                    float y3 = sm[O_PS + 3 * 128 + rr] + sm[O_PS + (6 + 3) * 128 + rr]
                             + sm[O_PS + (12 + 3) * 128 + rr] + sm[O_PS + (18 + 3) * 128 + rr];
                    float y4 = sm[O_PS + 4 * 128 + rr] + sm[O_PS + (6 + 4) * 128 + rr]
                             + sm[O_PS + (12 + 4) * 128 + rr] + sm[O_PS + (18 + 4) * 128 + rr];
                    float y5 = sm[O_PS + 5 * 128 + rr] + sm[O_PS + (6 + 5) * 128 + rr]
                             + sm[O_PS + (12 + 5) * 128 + rr] + sm[O_PS + (18 + 5) * 128 + rr];
                    const float* A0 = sm + sb + 6;
                    float sv = A0[0 * 6 + jj] * y0 + A0[1 * 6 + jj] * y1
                             + A0[2 * 6 + jj] * y2 + A0[3 * 6 + jj] * y3
                             + A0[4 * 6 + jj] * y4 + A0[5 * 6 + jj] * y5;
                    sm[O_T + jj * 128 + rr] = sm[O_SG1 + rr] * sv;
                }
            }
        }
        __syncthreads();
        // ---- S5: psum[c][j][r] = W1[r,chunk] . T1_j ----
        {
            float a0 = 0.f, a1 = 0.f, a2 = 0.f, a3 = 0.f, a4 = 0.f, a5 = 0.f;
            const float4* T4 = (const float4*)(sm + O_T);
            #pragma unroll
            for (int q = 0; q < 8; ++q) {
                int qq = c4 * 8 + (q ^ key);
                float4 w = W14[r * 32 + qq];
                a0 = dot4(w, T4[qq], a0);
                a1 = dot4(w, T4[32 + qq], a1);
                a2 = dot4(w, T4[64 + qq], a2);
                a3 = dot4(w, T4[96 + qq], a3);
                a4 = dot4(w, T4[128 + qq], a4);
                a5 = dot4(w, T4[160 + qq], a5);
            }
            sm[O_PS + (c4 * 6 + 0) * 128 + r] = a0;
            sm[O_PS + (c4 * 6 + 1) * 128 + r] = a1;
            sm[O_PS + (c4 * 6 + 2) * 128 + r] = a2;
            sm[O_PS + (c4 * 6 + 3) * 128 + r] = a3;
            sm[O_PS + (c4 * 6 + 4) * 128 + r] = a4;
            sm[O_PS + (c4 * 6 + 5) * 128 + r] = a5;
        }
        __syncthreads();
        // ---- R5: T2_j = sg2 .* sum_c ----
        {
            #pragma unroll
            for (int s = 0; s < 2; ++s) {
                int e = tid + s * 512;
                if (s == 0 || tid < 256) {
                    int jj = e >> 7, rr = e & 127;
                    float sv = sm[O_PS + jj * 128 + rr] + sm[O_PS + (6 + jj) * 128 + rr]
                             + sm[O_PS + (12 + jj) * 128 + rr] + sm[O_PS + (18 + jj) * 128 + rr];
                    sm[O_U + jj * 128 + rr] = sm[O_SG2 + rr] * sv;
                }
            }
        }
        __syncthreads();
        // ---- S6: psumV = W2 . T2_{j(row)} ----
        {
            float acc0 = 0.f, acc1 = 0.f, acc2 = 0.f;
            const float4* TA = (const float4*)(sm + O_U) + jA * 32 + kh * 16;
            const float4* TB = (const float4*)(sm + O_U) + jB * 32 + kh * 16;
            const float4* TC = (const float4*)(sm + O_U) + jC * 32 + kh * 16;
            #pragma unroll 4
            for (int i = 0; i < 16; ++i) {
                acc0 = dot4(WAp[i * 512], TA[i], acc0);
                acc1 = dot4(WBp[i * 512], TB[i], acc1);
                acc2 = dot4(WCp[i * 512], TC[i], acc2);
            }
            sm[O_PS + kh * 768 + r0] = acc0;
            sm[O_PS + kh * 768 + r1] = acc1;
            sm[O_PS + kh * 768 + r2] = acc2;
        }
        __syncthreads();
        // ---- H (merged R6): h += l1.V + sum_j (1-V^2)(psV0+psV1); hist; sig store ----
        if (tid < 128) {
            float xh = sm[O_H + tid];
            #pragma unroll
            for (int i = 0; i < 6; ++i)
                xh = fmaf(sm[sb + i], sm[O_V + i * 128 + tid], xh);
            #pragma unroll
            for (int j = 0; j < 6; ++j) {
                float v = sm[O_V + j * 128 + tid];
                xh += (1.f - v * v) * (sm[O_PS + j * 128 + tid] + sm[O_PS + 768 + j * 128 + tid]);
            }
            sm[O_H + tid] = xh;
            g_hist[(b * (NW + 1) + t + 1) * 128 + tid] = xh;
        }
        if (tid >= 448) {
            int q = tid - 448;
            if (q < 42 && t + 1 < NW)
                sm[O_SIG + ((t + 1) & 1) * 44 + q] = rsig;
        }
        __syncthreads();
    }
}

// ---- K4: readout ----
__global__ __launch_bounds__(384) void k_read(const float* __restrict__ Wr,
                                              const float* __restrict__ br,
                                              float* __restrict__ out) {
    const int b = blockIdx.x, e = threadIdx.x;
    if (e < (NW + 1) * OUTD) {
        int t = e / OUTD, o = e % OUTD;
        float z = br[o];
        const float4* hrow = (const float4*)&g_hist[(b * (NW + 1) + t) * 128];
        const float4* wrow = (const float4*)&Wr[o * 128];
        float z0 = 0, z1 = 0, z2 = 0, z3 = 0;
        #pragma unroll 8
        for (int s4 = 0; s4 < 32; ++s4) {
            float4 hv = hrow[s4]; float4 wv = wrow[s4];
            z0 = fmaf(hv.x, wv.x, z0); z1 = fmaf(hv.y, wv.y, z1);
            z2 = fmaf(hv.z, wv.z, z2); z3 = fmaf(hv.w, wv.w, z3);
        }
        out[(b * (NW + 1) + t) * OUTD + o] = z + ((z0 + z1) + (z2 + z3));
    }
}

extern "C" void kernel_launch(void* const* d_in, const int* in_sizes, int n_in,
                              void* d_out, int out_size, void* d_ws, size_t ws_size,
                              hipStream_t stream) {
    const float* x   = (const float*)d_in[0];
    const float* Wi0 = (const float*)d_in[1];
    const float* bi0 = (const float*)d_in[2];
    const float* Wi1 = (const float*)d_in[3];
    const float* bi1 = (const float*)d_in[4];
    const float* Wi2 = (const float*)d_in[5];
    const float* bi2 = (const float*)d_in[6];
    const float* Wv0 = (const float*)d_in[7];
    const float* bv0 = (const float*)d_in[8];
    const float* Wv1 = (const float*)d_in[9];
    const float* bv1 = (const float*)d_in[10];
    const float* Wv2 = (const float*)d_in[11];
    const float* bv2 = (const float*)d_in[12];
    const float* Wr  = (const float*)d_in[13];
    const float* br  = (const float*)d_in[14];
    float* out = (float*)d_out;

    hipLaunchKernelGGL(k_pack, dim3(48), dim3(512), 0, stream, Wv2);
    hipLaunchKernelGGL(k_sig,  dim3(BB), dim3(256), 0, stream,
                       x, Wi0, bi0, Wi1, bi1, Wi2, bi2);
    hipLaunchKernelGGL(k_scan, dim3(BB), dim3(512), 0, stream,
                       bv0, bv1, bv2, Wv0, Wv1);
    hipLaunchKernelGGL(k_read, dim3(BB), dim3(384), 0, stream, Wr, br, out);
}